// Round 10
// baseline (258.249 us; speedup 1.0000x reference)
//
#include <hip/hip_runtime.h>

#define L_ 1024
#define DM 1024

typedef float f32x4 __attribute__((ext_vector_type(4)));
typedef _Float16 f16;
typedef _Float16 f16x8 __attribute__((ext_vector_type(8)));
typedef _Float16 f16x4 __attribute__((ext_vector_type(4)));

// async global->LDS, 16B per lane. LDS dest must be wave-uniform base; HW adds lane*16.
__device__ __forceinline__ void gload16(const void* g, void* l) {
  __builtin_amdgcn_global_load_lds(
      (const __attribute__((address_space(1))) unsigned int*)g,
      (__attribute__((address_space(3))) unsigned int*)l, 16, 0, 0);
}

// ---------------- weight f32->f16 conversions (inputs converted inside proj_gemm) ----------------
__global__ __launch_bounds__(256) void cvt_w(const float* __restrict__ wq,
    const float* __restrict__ wk, const float* __restrict__ wv, const float* __restrict__ wo,
    f16* __restrict__ dw, f16* __restrict__ dwo) {
  int i = blockIdx.x * 256 + threadIdx.x;  // 8-elem units, 524288 total
  const float* s; f16* d; int off;
  if (i < 131072)       { s = wq; d = dw;             off = i; }
  else if (i < 262144)  { s = wk; d = dw + 1048576;   off = i - 131072; }
  else if (i < 393216)  { s = wv; d = dw + 2097152;   off = i - 262144; }
  else                  { s = wo; d = dwo;            off = i - 393216; }
  const float4* sp = (const float4*)s + (size_t)off * 2;
  float4 a = sp[0], bb = sp[1];
  f16x8 o;
  o[0] = (f16)a.x;  o[1] = (f16)a.y;  o[2] = (f16)a.z;  o[3] = (f16)a.w;
  o[4] = (f16)bb.x; o[5] = (f16)bb.y; o[6] = (f16)bb.z; o[7] = (f16)bb.w;
  ((f16x8*)d)[off] = o;
}

__global__ __launch_bounds__(256) void biascat(const float* __restrict__ bq,
    const float* __restrict__ bk, const float* __restrict__ bv, float* __restrict__ o) {
  int t = blockIdx.x * 256 + threadIdx.x;  // 3072
  o[t] = (t < 1024) ? bq[t] : (t < 2048) ? bk[t - 1024] : bv[t - 2048];
}

// ---------------- QKV projection: f32 A with fused cvt (reg-staged), f16 W via gload16 ----------
// 128x64 tiles, BK=64. grid (512,1,3). xcd=bid&7 owns 4 contiguous A-panels x all 16 N-tiles (T1).
// A LDS padded [128][36] (stride 18 banks) -> conflict-free writes and ~2-way reads.
__global__ __launch_bounds__(256) void proj_gemm(const float* __restrict__ Aq,
    const float* __restrict__ Ak, const float* __restrict__ Av,
    const f16* __restrict__ Wc, const float* __restrict__ bcat, f16* __restrict__ QKVp) {
  alignas(16) __shared__ f16 At0[128 * 36];
  alignas(16) __shared__ f16 At1[128 * 36];
  alignas(16) __shared__ f16 Bt0[64 * 32];
  alignas(16) __shared__ f16 Bt1[64 * 32];
  int z = blockIdx.z;
  const float* A = (z == 0) ? Aq : (z == 1) ? Ak : Av;
  const f16* W = Wc + (size_t)z * 1048576;
  int t = threadIdx.x, lane = t & 63;
  int w = t >> 6, wr = w >> 1, wc = w & 1;
  int bid = blockIdx.x;
  int xcd = bid & 7, local = bid >> 3;      // 64 blocks per XCD
  int bm = (xcd * 4 + (local >> 4)) * 128;  // 4 A-panels per XCD
  int bn = (local & 15) * 64;               // 16 N-tiles of 64
  f32x4 acc[4][2] = {};
  // A staging: thread covers row=t>>1, f32 cols (t&1)*32..+31 of the 64-wide k-slab
  int arow = t >> 1, ahalf = t & 1;
  const float4* gA = (const float4*)(A + (size_t)(bm + arow) * 1024 + ahalf * 32);
  f16* aDst = (ahalf ? At1 : At0) + arow * 36;
  // B staging (gload16): rows 16w+(lane>>2), col (lane&3)*8
  int rbB = 16 * w + (lane >> 2);
  int c8 = (lane & 3) * 8;
  const f16* gB = W + (size_t)(bn + rbB) * 1024 + c8;
  f16* lB0 = &Bt0[w * 512];
  f16* lB1 = &Bt1[w * 512];
  int roA = (lane & 15) * 36 + (lane >> 4) * 8;
  int roB = (lane & 15) * 32 + (lane >> 4) * 8;
  for (int kk = 0; kk < 1024; kk += 64) {
    gload16(gB + kk, lB0);
    gload16(gB + kk + 32, lB1);
    const float4* ga = gA + (kk >> 2);
    float4 v0 = ga[0], v1 = ga[1], v2 = ga[2], v3 = ga[3];
    float4 v4 = ga[4], v5 = ga[5], v6 = ga[6], v7 = ga[7];
    f16x8 o0, o1, o2, o3;
    o0[0] = (f16)v0.x; o0[1] = (f16)v0.y; o0[2] = (f16)v0.z; o0[3] = (f16)v0.w;
    o0[4] = (f16)v1.x; o0[5] = (f16)v1.y; o0[6] = (f16)v1.z; o0[7] = (f16)v1.w;
    o1[0] = (f16)v2.x; o1[1] = (f16)v2.y; o1[2] = (f16)v2.z; o1[3] = (f16)v2.w;
    o1[4] = (f16)v3.x; o1[5] = (f16)v3.y; o1[6] = (f16)v3.z; o1[7] = (f16)v3.w;
    o2[0] = (f16)v4.x; o2[1] = (f16)v4.y; o2[2] = (f16)v4.z; o2[3] = (f16)v4.w;
    o2[4] = (f16)v5.x; o2[5] = (f16)v5.y; o2[6] = (f16)v5.z; o2[7] = (f16)v5.w;
    o3[0] = (f16)v6.x; o3[1] = (f16)v6.y; o3[2] = (f16)v6.z; o3[3] = (f16)v6.w;
    o3[4] = (f16)v7.x; o3[5] = (f16)v7.y; o3[6] = (f16)v7.z; o3[7] = (f16)v7.w;
    *(f16x8*)&aDst[0]  = o0;
    *(f16x8*)&aDst[8]  = o1;
    *(f16x8*)&aDst[16] = o2;
    *(f16x8*)&aDst[24] = o3;
    __syncthreads();                      // drains vmcnt (gload16) + lgkm (ds_write)
    f16x8 af[4], af2[4], bf[2], bf2[2];
    #pragma unroll
    for (int m = 0; m < 4; ++m) {
      af[m]  = *(const f16x8*)&At0[(wr * 64 + m * 16) * 36 + roA];
      af2[m] = *(const f16x8*)&At1[(wr * 64 + m * 16) * 36 + roA];
    }
    #pragma unroll
    for (int n = 0; n < 2; ++n) {
      bf[n]  = *(const f16x8*)&Bt0[(wc * 32 + n * 16) * 32 + roB];
      bf2[n] = *(const f16x8*)&Bt1[(wc * 32 + n * 16) * 32 + roB];
    }
    #pragma unroll
    for (int m = 0; m < 4; ++m)
      #pragma unroll
      for (int n = 0; n < 2; ++n) {
        acc[m][n] = __builtin_amdgcn_mfma_f32_16x16x32_f16(af[m], bf[n], acc[m][n], 0, 0, 0);
        acc[m][n] = __builtin_amdgcn_mfma_f32_16x16x32_f16(af2[m], bf2[n], acc[m][n], 0, 0, 0);
      }
    __syncthreads();                      // reads done before next overwrite
  }
  float scale = (z == 0) ? 0.125f : 1.0f;
  #pragma unroll
  for (int n = 0; n < 2; ++n) {
    int cn = bn + wc * 32 + n * 16 + (lane & 15);
    float bvv = bcat[z * 1024 + cn];
    #pragma unroll
    for (int m = 0; m < 4; ++m) {
      int r0 = bm + wr * 64 + m * 16 + (lane >> 4) * 4;
      #pragma unroll
      for (int r = 0; r < 4; ++r)
        QKVp[(size_t)(r0 + r) * 3072 + z * 1024 + cn] = (f16)((acc[m][n][r] + bvv) * scale);
    }
  }
}

// ---------------- output projection (f32 out): 128x64 tiles, BK=64, XCD-swizzled ----------------
__global__ __launch_bounds__(256) void gemm_out(const f16* __restrict__ A,
    const f16* __restrict__ W, const float* __restrict__ bias, float* __restrict__ C) {
  alignas(16) __shared__ f16 At0[128 * 32];
  alignas(16) __shared__ f16 At1[128 * 32];
  alignas(16) __shared__ f16 Bt0[64 * 32];
  alignas(16) __shared__ f16 Bt1[64 * 32];
  int t = threadIdx.x, lane = t & 63;
  int w = t >> 6, wr = w >> 1, wc = w & 1;
  int bid = blockIdx.x;
  int xcd = bid & 7, local = bid >> 3;
  int bm = (xcd * 4 + (local >> 4)) * 128;
  int bn = (local & 15) * 64;
  f32x4 acc[4][2] = {};
  int rbA = 32 * w + (lane >> 2);
  int rbB = 16 * w + (lane >> 2);
  int c8 = (lane & 3) * 8;
  const f16* gA = A + (size_t)(bm + rbA) * 1024 + c8;
  const f16* gB = W + (size_t)(bn + rbB) * 1024 + c8;
  f16* lA00 = &At0[(2 * w) * 512];      f16* lA01 = &At0[(2 * w + 1) * 512];
  f16* lA10 = &At1[(2 * w) * 512];      f16* lA11 = &At1[(2 * w + 1) * 512];
  f16* lB0  = &Bt0[w * 512];            f16* lB1  = &Bt1[w * 512];
  int ro = (lane & 15) * 32 + (lane >> 4) * 8;
  for (int kk = 0; kk < 1024; kk += 64) {
    gload16(gA + kk, lA00);
    gload16(gA + 16 * 1024 + kk, lA01);
    gload16(gA + kk + 32, lA10);
    gload16(gA + 16 * 1024 + kk + 32, lA11);
    gload16(gB + kk, lB0);
    gload16(gB + kk + 32, lB1);
    __syncthreads();
    f16x8 af[4], af2[4], bf[2], bf2[2];
    #pragma unroll
    for (int m = 0; m < 4; ++m) {
      af[m]  = *(const f16x8*)&At0[(wr * 64 + m * 16) * 32 + ro];
      af2[m] = *(const f16x8*)&At1[(wr * 64 + m * 16) * 32 + ro];
    }
    #pragma unroll
    for (int n = 0; n < 2; ++n) {
      bf[n]  = *(const f16x8*)&Bt0[(wc * 32 + n * 16) * 32 + ro];
      bf2[n] = *(const f16x8*)&Bt1[(wc * 32 + n * 16) * 32 + ro];
    }
    #pragma unroll
    for (int m = 0; m < 4; ++m)
      #pragma unroll
      for (int n = 0; n < 2; ++n) {
        acc[m][n] = __builtin_amdgcn_mfma_f32_16x16x32_f16(af[m], bf[n], acc[m][n], 0, 0, 0);
        acc[m][n] = __builtin_amdgcn_mfma_f32_16x16x32_f16(af2[m], bf2[n], acc[m][n], 0, 0, 0);
      }
    __syncthreads();
  }
  #pragma unroll
  for (int n = 0; n < 2; ++n) {
    int cn = bn + wc * 32 + n * 16 + (lane & 15);
    float bvv = bias[cn];
    #pragma unroll
    for (int m = 0; m < 4; ++m) {
      int r0 = bm + wr * 64 + m * 16 + (lane >> 4) * 4;
      #pragma unroll
      for (int r = 0; r < 4; ++r)
        C[(size_t)(r0 + r) * 1024 + cn] = acc[m][n][r] + bvv;
    }
  }
}

// ---------------- V section of QKVp -> Vt [(b*16+h)*64 + d][k] ----------------
__global__ __launch_bounds__(256) void transpose_v(const f16* __restrict__ QKVp,
                                                   f16* __restrict__ Vt) {
  alignas(16) __shared__ f16 T[64 * 72];
  int bh = blockIdx.y;
  int b = bh >> 4, h = bh & 15;
  int kt = blockIdx.x;
  int t = threadIdx.x;
  int krow = t >> 2, part = t & 3;
  const f16x8* src = (const f16x8*)(QKVp + (size_t)(b * L_ + kt * 64 + krow) * 3072 + 2048 + h * 64 + part * 16);
  f16x8 v0 = src[0], v1 = src[1];
  *(f16x8*)&T[krow * 72 + part * 16] = v0;
  *(f16x8*)&T[krow * 72 + part * 16 + 8] = v1;
  __syncthreads();
  int drow = t >> 2;
  f16x8 o0, o1;
  #pragma unroll
  for (int j = 0; j < 8; ++j) o0[j] = T[(part * 16 + j) * 72 + drow];
  #pragma unroll
  for (int j = 0; j < 8; ++j) o1[j] = T[(part * 16 + 8 + j) * 72 + drow];
  f16* dst = Vt + (size_t)(bh * 64 + drow) * L_ + kt * 64 + part * 16;
  *(f16x8*)dst = o0;
  *(f16x8*)(dst + 8) = o1;
}

// ---------------- cb[b][q][g] = sum_h attn_bias[b][h][q]*Wl[g][h] + bl[g] ----------------
__global__ __launch_bounds__(256) void cbias_kernel(const float* __restrict__ ab,
    const float* __restrict__ Wl, const float* __restrict__ bl, float* __restrict__ cb) {
  int t = blockIdx.x * 256 + threadIdx.x;  // 65536
  int b = t >> 14, q = (t >> 4) & 1023, g = t & 15;
  float s = bl[g];
  #pragma unroll
  for (int h = 0; h < 16; ++h) s += ab[(size_t)(b * 16 + h) * L_ + q] * Wl[g * 16 + h];
  cb[t] = s;
}

// ---------------- S[bz][h][q][k] = Qh @ Kh^T (K=64); grid (kt8, qt8, bz*16+h) ----------------
__global__ __launch_bounds__(256) void qk_gemm(const f16* __restrict__ QKVp,
                                               f16* __restrict__ S, int b0) {
  alignas(16) __shared__ f16 At[128 * 72];
  alignas(16) __shared__ f16 Bt[128 * 72];
  int t = threadIdx.x, lane = t & 63;
  int wid = t >> 6, wr = wid >> 1, wc = wid & 1;
  int kt = blockIdx.x, qt = blockIdx.y;
  int h = blockIdx.z & 15, bz = blockIdx.z >> 4;
  int b = b0 + bz;
  #pragma unroll
  for (int i = 0; i < 4; ++i) {
    int row = i * 32 + (t >> 3), c = (t & 7) * 8;
    *(f16x8*)&At[row * 72 + c] =
        *(const f16x8*)(QKVp + (size_t)(b * 1024 + qt * 128 + row) * 3072 + h * 64 + c);
    *(f16x8*)&Bt[row * 72 + c] =
        *(const f16x8*)(QKVp + (size_t)(b * 1024 + kt * 128 + row) * 3072 + 1024 + h * 64 + c);
  }
  __syncthreads();
  int l15 = lane & 15, lhi = lane >> 4;
  f32x4 acc[4][4] = {};
  #pragma unroll
  for (int s = 0; s < 2; ++s) {
    f16x8 af[4], bf[4];
    #pragma unroll
    for (int m = 0; m < 4; ++m) af[m] = *(const f16x8*)&At[(wr * 64 + m * 16 + l15) * 72 + s * 32 + lhi * 8];
    #pragma unroll
    for (int n = 0; n < 4; ++n) bf[n] = *(const f16x8*)&Bt[(wc * 64 + n * 16 + l15) * 72 + s * 32 + lhi * 8];
    #pragma unroll
    for (int m = 0; m < 4; ++m)
      #pragma unroll
      for (int n = 0; n < 4; ++n)
        acc[m][n] = __builtin_amdgcn_mfma_f32_16x16x32_f16(af[m], bf[n], acc[m][n], 0, 0, 0);
  }
  size_t Sh = (size_t)(bz * 16 + h) * 1048576;
  #pragma unroll
  for (int n = 0; n < 4; ++n) {
    int col = kt * 128 + wc * 64 + n * 16 + l15;
    #pragma unroll
    for (int m = 0; m < 4; ++m) {
      int q0 = qt * 128 + wr * 64 + m * 16 + lhi * 4;
      #pragma unroll
      for (int r = 0; r < 4; ++r)
        S[Sh + (size_t)(q0 + r) * 1024 + col] = (f16)acc[m][n][r];
    }
  }
}

// ---------------- fused mix1 + softmax + mix2, fully in-place in one LDS buffer ----------------
__global__ __launch_bounds__(256) void msm_kernel(f16* __restrict__ S,
    const float* __restrict__ Wl, const float* __restrict__ Ww,
    const float* __restrict__ bwv, const float* __restrict__ cb, int b0) {
  alignas(16) __shared__ f16 Sl[16][1032];   // S -> E -> w, in place
  __shared__ float red[4][16];
  __shared__ float rlv16[16];
  int t = threadIdx.x;
  int q = blockIdx.x & 1023, bz = blockIdx.x >> 10;
  int lane = t & 63, w = t >> 6, l15 = lane & 15, lhi = lane >> 4;
  size_t Sq = (size_t)(bz * 16) * 1048576 + (size_t)q * 1024;
  #pragma unroll
  for (int i = 0; i < 8; ++i) {
    int idx = i * 256 + t, h = idx >> 7, c = (idx & 127) * 8;
    *(f16x8*)&Sl[h][c] = *(const f16x8*)(S + Sq + (size_t)h * 1048576 + c);
  }
  // B1[h][g] = Wl[g,h]; lane: col g=l15, rows h=lhi*4+j
  f16x4 b1;
  #pragma unroll
  for (int j = 0; j < 4; ++j) b1[j] = (f16)Wl[l15 * 16 + lhi * 4 + j];
  float cbv = cb[((size_t)((b0 + bz) * 1024 + q)) * 16 + l15];
  __syncthreads();
  // phase 1: logits = S^T x Wl^T, exp, denom; E written in place as rows [g][k]
  float dsum = 0.f;
  for (int i = 0; i < 16; ++i) {
    int kt = w * 16 + i;
    int krow = kt * 16 + l15;
    f16x4 a1;  // A[k][h]: row k=krow, cols h=lhi*4+j
    #pragma unroll
    for (int j = 0; j < 4; ++j) a1[j] = Sl[lhi * 4 + j][krow];
    f32x4 d = __builtin_amdgcn_mfma_f32_16x16x16f16(a1, b1, (f32x4){0.f, 0.f, 0.f, 0.f}, 0, 0, 0);
    int k0 = kt * 16 + lhi * 4;  // D: col g=l15, row k=k0+r
    f16x4 ev;
    #pragma unroll
    for (int r = 0; r < 4; ++r) {
      float e = __expf(d[r] + cbv);
      dsum += e;
      ev[r] = (f16)e;
    }
    *(f16x4*)&Sl[l15][k0] = ev;   // E[g=l15][k0..k0+3], within this wave's k-stripe
  }
  dsum += __shfl_xor(dsum, 16);
  dsum += __shfl_xor(dsum, 32);
  if (lane < 16) red[w][lane] = dsum;
  __syncthreads();
  if (t < 16) rlv16[t] = 1.0f / (red[0][t] + red[1][t] + red[2][t] + red[3][t]);
  __syncthreads();
  // B2[g][h] = Ww[h,g]*rlv[g]; lane: col h=l15, rows g=lhi*4+j
  f16x4 b2;
  #pragma unroll
  for (int j = 0; j < 4; ++j) b2[j] = (f16)(Ww[l15 * 16 + lhi * 4 + j] * rlv16[lhi * 4 + j]);
  float bwh = bwv[l15];
  // phase 2: w = E x (rlv*Ww) + bw, written in place as rows [h][k]
  for (int i = 0; i < 16; ++i) {
    int kt = w * 16 + i;
    int krow = kt * 16 + l15;
    f16x4 a2;  // A[k][g] = E: row k=krow, cols g=lhi*4+j  (stored as Sl[g][k])
    #pragma unroll
    for (int j = 0; j < 4; ++j) a2[j] = Sl[lhi * 4 + j][krow];
    f32x4 d = __builtin_amdgcn_mfma_f32_16x16x16f16(a2, b2, (f32x4){0.f, 0.f, 0.f, 0.f}, 0, 0, 0);
    int k0 = kt * 16 + lhi * 4;  // D: col h=l15, row k=k0+r
    f16x4 wv4;
    #pragma unroll
    for (int r = 0; r < 4; ++r) wv4[r] = (f16)(d[r] + bwh);
    *(f16x4*)&Sl[l15][k0] = wv4;  // w[h=l15][k0..k0+3]
  }
  __syncthreads();
  #pragma unroll
  for (int i = 0; i < 8; ++i) {
    int idx = i * 256 + t, h = idx >> 7, c = (idx & 127) * 8;
    *(f16x8*)(S + Sq + (size_t)h * 1048576 + c) = *(f16x8*)&Sl[h][c];
  }
}

// ---------------- ctx[b*1024+q][h*64+d] = w[h][q][:] @ V[h][:][d]; grid (qt32, h16, bz) ----------------
__global__ __launch_bounds__(256) void pv_gemm(const f16* __restrict__ Sw,
    const f16* __restrict__ Vt, f16* __restrict__ ctx, int b0) {
  alignas(16) __shared__ f16 Aw[32 * 72];
  alignas(16) __shared__ f16 Bv[64 * 72];
  int t = threadIdx.x, lane = t & 63, w = t >> 6;
  int qt = blockIdx.x, h = blockIdx.y, bz = blockIdx.z;
  int wr = w >> 1, wc = w & 1;
  int l15 = lane & 15, lhi = lane >> 4;
  const f16* Sh = Sw + (size_t)(bz * 16 + h) * 1048576 + (size_t)(qt * 32) * 1024;
  const f16* Vh = Vt + (size_t)((b0 + bz) * 16 + h) * 64 * 1024;
  f32x4 acc[2] = {};
  int srow = t >> 3, scol = (t & 7) * 8;
  for (int kk = 0; kk < 1024; kk += 64) {
    __syncthreads();
    *(f16x8*)&Aw[srow * 72 + scol] = *(const f16x8*)(Sh + (size_t)srow * 1024 + kk + scol);
    *(f16x8*)&Bv[srow * 72 + scol] = *(const f16x8*)(Vh + (size_t)srow * 1024 + kk + scol);
    *(f16x8*)&Bv[(srow + 32) * 72 + scol] = *(const f16x8*)(Vh + (size_t)(srow + 32) * 1024 + kk + scol);
    __syncthreads();
    #pragma unroll
    for (int s = 0; s < 2; ++s) {
      f16x8 af = *(const f16x8*)&Aw[(wr * 16 + l15) * 72 + s * 32 + lhi * 8];
      #pragma unroll
      for (int n = 0; n < 2; ++n) {
        f16x8 bf = *(const f16x8*)&Bv[(wc * 32 + n * 16 + l15) * 72 + s * 32 + lhi * 8];
        acc[n] = __builtin_amdgcn_mfma_f32_16x16x32_f16(af, bf, acc[n], 0, 0, 0);
      }
    }
  }
  #pragma unroll
  for (int n = 0; n < 2; ++n) {
    int col = h * 64 + wc * 32 + n * 16 + l15;
    int q0 = (b0 + bz) * 1024 + qt * 32 + wr * 16 + lhi * 4;
    #pragma unroll
    for (int r = 0; r < 4; ++r)
      ctx[(size_t)(q0 + r) * 1024 + col] = (f16)acc[n][r];
  }
}

extern "C" void kernel_launch(void* const* d_in, const int* in_sizes, int n_in,
                              void* d_out, int out_size, void* d_ws, size_t ws_size,
                              hipStream_t stream) {
  const float* queries = (const float*)d_in[0];
  const float* keys    = (const float*)d_in[1];
  const float* values  = (const float*)d_in[2];
  const float* ab  = (const float*)d_in[4];
  const float* Wq  = (const float*)d_in[5];  const float* bq = (const float*)d_in[6];
  const float* Wk  = (const float*)d_in[7];  const float* bk = (const float*)d_in[8];
  const float* Wv  = (const float*)d_in[9];  const float* bv = (const float*)d_in[10];
  const float* Wl  = (const float*)d_in[11]; const float* bl = (const float*)d_in[12];
  const float* Ww  = (const float*)d_in[13]; const float* bwp = (const float*)d_in[14];
  const float* Wo  = (const float*)d_in[15]; const float* bo = (const float*)d_in[16];

  char* ws = (char*)d_ws;
  const size_t MB = 1024 * 1024;
  bool full = ws_size >= 172 * MB;  // deterministic path choice

  f16* wqkv  = (f16*)(ws + 24 * MB);       // 6 MB (dead after proj; overlapped by S later)
  f16* S     = (f16*)(ws + 0 * MB);        // full: 128 MB; chunked: 32 MB per b
  f16* QKVp  = (f16*)(ws + (full ? 128 : 32) * MB);   // 24 MB
  f16* Vt    = (f16*)(ws + (full ? 152 : 56) * MB);   // 8 MB
  float* cbp = (float*)(ws + (full ? 170 : 64) * MB); // 256 KB
  f16* wo16  = (f16*)(ws + (full ? 168 : 65) * MB);   // 2 MB
  f16* ctx   = (f16*)(ws + (full ? 160 : 67) * MB);   // 8 MB
  float* bqkv = (float*)(ws + (full ? 170 * MB + 512 * 1024 : 30 * MB));  // 12 KB

  cvt_w<<<2048, 256, 0, stream>>>(Wq, Wk, Wv, Wo, wqkv, wo16);
  biascat<<<12, 256, 0, stream>>>(bq, bk, bv, bqkv);
  proj_gemm<<<dim3(512, 1, 3), 256, 0, stream>>>(queries, keys, values, wqkv, bqkv, QKVp);
  transpose_v<<<dim3(16, 64), 256, 0, stream>>>(QKVp, Vt);
  cbias_kernel<<<256, 256, 0, stream>>>(ab, Wl, bl, cbp);

  if (full) {
    qk_gemm<<<dim3(8, 8, 64), 256, 0, stream>>>(QKVp, S, 0);
    msm_kernel<<<4096, 256, 0, stream>>>(S, Wl, Ww, bwp, cbp, 0);
    pv_gemm<<<dim3(32, 16, 4), 256, 0, stream>>>(S, Vt, ctx, 0);
  } else {
    for (int b = 0; b < 4; ++b) {
      qk_gemm<<<dim3(8, 8, 16), 256, 0, stream>>>(QKVp, S, b);
      msm_kernel<<<1024, 256, 0, stream>>>(S, Wl, Ww, bwp, cbp, b);
      pv_gemm<<<dim3(32, 16, 1), 256, 0, stream>>>(S, Vt, ctx, b);
    }
  }

  gemm_out<<<dim3(512), 256, 0, stream>>>(ctx, wo16, bo, (float*)d_out);
}

// Round 11
// 196.321 us; speedup vs baseline: 1.3154x; 1.3154x over previous
//
#include <hip/hip_runtime.h>

#define L_ 1024
#define DM 1024

typedef float f32x4 __attribute__((ext_vector_type(4)));
typedef _Float16 f16;
typedef _Float16 f16x8 __attribute__((ext_vector_type(8)));
typedef _Float16 f16x4 __attribute__((ext_vector_type(4)));

// async global->LDS, 16B per lane. LDS dest must be wave-uniform base; HW adds lane*16.
__device__ __forceinline__ void gload16(const void* g, void* l) {
  __builtin_amdgcn_global_load_lds(
      (const __attribute__((address_space(1))) unsigned int*)g,
      (__attribute__((address_space(3))) unsigned int*)l, 16, 0, 0);
}

// ---------------- all f32->f16 conversions in one launch ----------------
__global__ __launch_bounds__(256) void cvt_all(const float* __restrict__ q,
    const float* __restrict__ k, const float* __restrict__ v,
    const float* __restrict__ wq, const float* __restrict__ wk,
    const float* __restrict__ wv, const float* __restrict__ wo,
    f16* __restrict__ dbig, f16* __restrict__ dw, f16* __restrict__ dwo) {
  int i = blockIdx.x * 256 + threadIdx.x;  // 8-elem units, 2097152 total
  const float* s; f16* d; int off;
  if (i < 524288)       { s = q;  d = dbig;           off = i; }
  else if (i < 1048576) { s = k;  d = dbig + 4194304; off = i - 524288; }
  else if (i < 1572864) { s = v;  d = dbig + 8388608; off = i - 1048576; }
  else if (i < 1703936) { s = wq; d = dw;             off = i - 1572864; }
  else if (i < 1835008) { s = wk; d = dw + 1048576;   off = i - 1703936; }
  else if (i < 1966080) { s = wv; d = dw + 2097152;   off = i - 1835008; }
  else                  { s = wo; d = dwo;            off = i - 1966080; }
  const float4* sp = (const float4*)s + (size_t)off * 2;
  float4 a = sp[0], bb = sp[1];
  f16x8 o;
  o[0] = (f16)a.x;  o[1] = (f16)a.y;  o[2] = (f16)a.z;  o[3] = (f16)a.w;
  o[4] = (f16)bb.x; o[5] = (f16)bb.y; o[6] = (f16)bb.z; o[7] = (f16)bb.w;
  ((f16x8*)d)[off] = o;
}

__global__ __launch_bounds__(256) void biascat(const float* __restrict__ bq,
    const float* __restrict__ bk, const float* __restrict__ bv, float* __restrict__ o) {
  int t = blockIdx.x * 256 + threadIdx.x;  // 3072
  o[t] = (t < 1024) ? bq[t] : (t < 2048) ? bk[t - 1024] : bv[t - 2048];
}

// ---------------- QKV projection: 128x64 tiles, BK=64, gload16, XCD-swizzled ----------------
// grid (512,1,3). xcd=bid&7 owns 4 contiguous A-panels x all 16 N-tiles (T1, bijective 512=8*64).
__global__ __launch_bounds__(256) void proj_gemm(const f16* __restrict__ Ain,
    const f16* __restrict__ Wc, const float* __restrict__ bcat, f16* __restrict__ QKVp) {
  alignas(16) __shared__ f16 At0[128 * 32];
  alignas(16) __shared__ f16 At1[128 * 32];
  alignas(16) __shared__ f16 Bt0[64 * 32];
  alignas(16) __shared__ f16 Bt1[64 * 32];
  int z = blockIdx.z;
  const f16* A = Ain + (size_t)z * 4194304;
  const f16* W = Wc + (size_t)z * 1048576;
  int t = threadIdx.x, lane = t & 63;
  int w = t >> 6, wr = w >> 1, wc = w & 1;
  int bid = blockIdx.x;
  int xcd = bid & 7, local = bid >> 3;      // 64 blocks per XCD
  int bm = (xcd * 4 + (local >> 4)) * 128;  // 4 A-panels per XCD
  int bn = (local & 15) * 64;               // 16 N-tiles of 64
  f32x4 acc[4][2] = {};
  int rbA = 32 * w + (lane >> 2);
  int rbB = 16 * w + (lane >> 2);
  int c8 = (lane & 3) * 8;
  const f16* gA = A + (size_t)(bm + rbA) * 1024 + c8;
  const f16* gB = W + (size_t)(bn + rbB) * 1024 + c8;
  f16* lA00 = &At0[(2 * w) * 512];      f16* lA01 = &At0[(2 * w + 1) * 512];
  f16* lA10 = &At1[(2 * w) * 512];      f16* lA11 = &At1[(2 * w + 1) * 512];
  f16* lB0  = &Bt0[w * 512];            f16* lB1  = &Bt1[w * 512];
  int ro = (lane & 15) * 32 + (lane >> 4) * 8;
  for (int kk = 0; kk < 1024; kk += 64) {
    gload16(gA + kk, lA00);
    gload16(gA + 16 * 1024 + kk, lA01);
    gload16(gA + kk + 32, lA10);
    gload16(gA + 16 * 1024 + kk + 32, lA11);
    gload16(gB + kk, lB0);
    gload16(gB + kk + 32, lB1);
    __syncthreads();                      // drains vmcnt -> tiles resident
    f16x8 af[4], af2[4], bf[2], bf2[2];
    #pragma unroll
    for (int m = 0; m < 4; ++m) {
      af[m]  = *(const f16x8*)&At0[(wr * 64 + m * 16) * 32 + ro];
      af2[m] = *(const f16x8*)&At1[(wr * 64 + m * 16) * 32 + ro];
    }
    #pragma unroll
    for (int n = 0; n < 2; ++n) {
      bf[n]  = *(const f16x8*)&Bt0[(wc * 32 + n * 16) * 32 + ro];
      bf2[n] = *(const f16x8*)&Bt1[(wc * 32 + n * 16) * 32 + ro];
    }
    #pragma unroll
    for (int m = 0; m < 4; ++m)
      #pragma unroll
      for (int n = 0; n < 2; ++n) {
        acc[m][n] = __builtin_amdgcn_mfma_f32_16x16x32_f16(af[m], bf[n], acc[m][n], 0, 0, 0);
        acc[m][n] = __builtin_amdgcn_mfma_f32_16x16x32_f16(af2[m], bf2[n], acc[m][n], 0, 0, 0);
      }
    __syncthreads();                      // reads done before next overwrite
  }
  float scale = (z == 0) ? 0.125f : 1.0f;
  #pragma unroll
  for (int n = 0; n < 2; ++n) {
    int cn = bn + wc * 32 + n * 16 + (lane & 15);
    float bvv = bcat[z * 1024 + cn];
    #pragma unroll
    for (int m = 0; m < 4; ++m) {
      int r0 = bm + wr * 64 + m * 16 + (lane >> 4) * 4;
      #pragma unroll
      for (int r = 0; r < 4; ++r)
        QKVp[(size_t)(r0 + r) * 3072 + z * 1024 + cn] = (f16)((acc[m][n][r] + bvv) * scale);
    }
  }
}

// ---------------- output projection (f32 out): 128x64 tiles, BK=64, XCD-swizzled ----------------
// grid 512 = 8 XCD * 64; each XCD owns 4 A-panels x 16 N-tiles.
__global__ __launch_bounds__(256) void gemm_out(const f16* __restrict__ A,
    const f16* __restrict__ W, const float* __restrict__ bias, float* __restrict__ C) {
  alignas(16) __shared__ f16 At0[128 * 32];
  alignas(16) __shared__ f16 At1[128 * 32];
  alignas(16) __shared__ f16 Bt0[64 * 32];
  alignas(16) __shared__ f16 Bt1[64 * 32];
  int t = threadIdx.x, lane = t & 63;
  int w = t >> 6, wr = w >> 1, wc = w & 1;
  int bid = blockIdx.x;
  int xcd = bid & 7, local = bid >> 3;
  int bm = (xcd * 4 + (local >> 4)) * 128;
  int bn = (local & 15) * 64;
  f32x4 acc[4][2] = {};
  int rbA = 32 * w + (lane >> 2);
  int rbB = 16 * w + (lane >> 2);
  int c8 = (lane & 3) * 8;
  const f16* gA = A + (size_t)(bm + rbA) * 1024 + c8;
  const f16* gB = W + (size_t)(bn + rbB) * 1024 + c8;
  f16* lA00 = &At0[(2 * w) * 512];      f16* lA01 = &At0[(2 * w + 1) * 512];
  f16* lA10 = &At1[(2 * w) * 512];      f16* lA11 = &At1[(2 * w + 1) * 512];
  f16* lB0  = &Bt0[w * 512];            f16* lB1  = &Bt1[w * 512];
  int ro = (lane & 15) * 32 + (lane >> 4) * 8;
  for (int kk = 0; kk < 1024; kk += 64) {
    gload16(gA + kk, lA00);
    gload16(gA + 16 * 1024 + kk, lA01);
    gload16(gA + kk + 32, lA10);
    gload16(gA + 16 * 1024 + kk + 32, lA11);
    gload16(gB + kk, lB0);
    gload16(gB + kk + 32, lB1);
    __syncthreads();
    f16x8 af[4], af2[4], bf[2], bf2[2];
    #pragma unroll
    for (int m = 0; m < 4; ++m) {
      af[m]  = *(const f16x8*)&At0[(wr * 64 + m * 16) * 32 + ro];
      af2[m] = *(const f16x8*)&At1[(wr * 64 + m * 16) * 32 + ro];
    }
    #pragma unroll
    for (int n = 0; n < 2; ++n) {
      bf[n]  = *(const f16x8*)&Bt0[(wc * 32 + n * 16) * 32 + ro];
      bf2[n] = *(const f16x8*)&Bt1[(wc * 32 + n * 16) * 32 + ro];
    }
    #pragma unroll
    for (int m = 0; m < 4; ++m)
      #pragma unroll
      for (int n = 0; n < 2; ++n) {
        acc[m][n] = __builtin_amdgcn_mfma_f32_16x16x32_f16(af[m], bf[n], acc[m][n], 0, 0, 0);
        acc[m][n] = __builtin_amdgcn_mfma_f32_16x16x32_f16(af2[m], bf2[n], acc[m][n], 0, 0, 0);
      }
    __syncthreads();
  }
  #pragma unroll
  for (int n = 0; n < 2; ++n) {
    int cn = bn + wc * 32 + n * 16 + (lane & 15);
    float bvv = bias[cn];
    #pragma unroll
    for (int m = 0; m < 4; ++m) {
      int r0 = bm + wr * 64 + m * 16 + (lane >> 4) * 4;
      #pragma unroll
      for (int r = 0; r < 4; ++r)
        C[(size_t)(r0 + r) * 1024 + cn] = acc[m][n][r] + bvv;
    }
  }
}

// ---------------- V section of QKVp -> Vt [(b*16+h)*64 + d][k] ----------------
__global__ __launch_bounds__(256) void transpose_v(const f16* __restrict__ QKVp,
                                                   f16* __restrict__ Vt) {
  alignas(16) __shared__ f16 T[64 * 72];
  int bh = blockIdx.y;
  int b = bh >> 4, h = bh & 15;
  int kt = blockIdx.x;
  int t = threadIdx.x;
  int krow = t >> 2, part = t & 3;
  const f16x8* src = (const f16x8*)(QKVp + (size_t)(b * L_ + kt * 64 + krow) * 3072 + 2048 + h * 64 + part * 16);
  f16x8 v0 = src[0], v1 = src[1];
  *(f16x8*)&T[krow * 72 + part * 16] = v0;
  *(f16x8*)&T[krow * 72 + part * 16 + 8] = v1;
  __syncthreads();
  int drow = t >> 2;
  f16x8 o0, o1;
  #pragma unroll
  for (int j = 0; j < 8; ++j) o0[j] = T[(part * 16 + j) * 72 + drow];
  #pragma unroll
  for (int j = 0; j < 8; ++j) o1[j] = T[(part * 16 + 8 + j) * 72 + drow];
  f16* dst = Vt + (size_t)(bh * 64 + drow) * L_ + kt * 64 + part * 16;
  *(f16x8*)dst = o0;
  *(f16x8*)(dst + 8) = o1;
}

// ---------------- cb[b][q][g] = sum_h attn_bias[b][h][q]*Wl[g][h] + bl[g] ----------------
__global__ __launch_bounds__(256) void cbias_kernel(const float* __restrict__ ab,
    const float* __restrict__ Wl, const float* __restrict__ bl, float* __restrict__ cb) {
  int t = blockIdx.x * 256 + threadIdx.x;  // 65536
  int b = t >> 14, q = (t >> 4) & 1023, g = t & 15;
  float s = bl[g];
  #pragma unroll
  for (int h = 0; h < 16; ++h) s += ab[(size_t)(b * 16 + h) * L_ + q] * Wl[g * 16 + h];
  cb[t] = s;
}

// ---------------- S[bz][h][q][k] = Qh @ Kh^T (K=64); grid (kt8, qt8, bz*16+h) ----------------
__global__ __launch_bounds__(256) void qk_gemm(const f16* __restrict__ QKVp,
                                               f16* __restrict__ S, int b0) {
  alignas(16) __shared__ f16 At[128 * 72];
  alignas(16) __shared__ f16 Bt[128 * 72];
  int t = threadIdx.x, lane = t & 63;
  int wid = t >> 6, wr = wid >> 1, wc = wid & 1;
  int kt = blockIdx.x, qt = blockIdx.y;
  int h = blockIdx.z & 15, bz = blockIdx.z >> 4;
  int b = b0 + bz;
  #pragma unroll
  for (int i = 0; i < 4; ++i) {
    int row = i * 32 + (t >> 3), c = (t & 7) * 8;
    *(f16x8*)&At[row * 72 + c] =
        *(const f16x8*)(QKVp + (size_t)(b * 1024 + qt * 128 + row) * 3072 + h * 64 + c);
    *(f16x8*)&Bt[row * 72 + c] =
        *(const f16x8*)(QKVp + (size_t)(b * 1024 + kt * 128 + row) * 3072 + 1024 + h * 64 + c);
  }
  __syncthreads();
  int l15 = lane & 15, lhi = lane >> 4;
  f32x4 acc[4][4] = {};
  #pragma unroll
  for (int s = 0; s < 2; ++s) {
    f16x8 af[4], bf[4];
    #pragma unroll
    for (int m = 0; m < 4; ++m) af[m] = *(const f16x8*)&At[(wr * 64 + m * 16 + l15) * 72 + s * 32 + lhi * 8];
    #pragma unroll
    for (int n = 0; n < 4; ++n) bf[n] = *(const f16x8*)&Bt[(wc * 64 + n * 16 + l15) * 72 + s * 32 + lhi * 8];
    #pragma unroll
    for (int m = 0; m < 4; ++m)
      #pragma unroll
      for (int n = 0; n < 4; ++n)
        acc[m][n] = __builtin_amdgcn_mfma_f32_16x16x32_f16(af[m], bf[n], acc[m][n], 0, 0, 0);
  }
  size_t Sh = (size_t)(bz * 16 + h) * 1048576;
  #pragma unroll
  for (int n = 0; n < 4; ++n) {
    int col = kt * 128 + wc * 64 + n * 16 + l15;
    #pragma unroll
    for (int m = 0; m < 4; ++m) {
      int q0 = qt * 128 + wr * 64 + m * 16 + lhi * 4;
      #pragma unroll
      for (int r = 0; r < 4; ++r)
        S[Sh + (size_t)(q0 + r) * 1024 + col] = (f16)acc[m][n][r];
    }
  }
}

// ---------------- fused mix1 + softmax + mix2, fully in-place in one LDS buffer ----------------
__global__ __launch_bounds__(256) void msm_kernel(f16* __restrict__ S,
    const float* __restrict__ Wl, const float* __restrict__ Ww,
    const float* __restrict__ bwv, const float* __restrict__ cb, int b0) {
  alignas(16) __shared__ f16 Sl[16][1032];   // S -> E -> w, in place
  __shared__ float red[4][16];
  __shared__ float rlv16[16];
  int t = threadIdx.x;
  int q = blockIdx.x & 1023, bz = blockIdx.x >> 10;
  int lane = t & 63, w = t >> 6, l15 = lane & 15, lhi = lane >> 4;
  size_t Sq = (size_t)(bz * 16) * 1048576 + (size_t)q * 1024;
  #pragma unroll
  for (int i = 0; i < 8; ++i) {
    int idx = i * 256 + t, h = idx >> 7, c = (idx & 127) * 8;
    *(f16x8*)&Sl[h][c] = *(const f16x8*)(S + Sq + (size_t)h * 1048576 + c);
  }
  // B1[h][g] = Wl[g,h]; lane: col g=l15, rows h=lhi*4+j
  f16x4 b1;
  #pragma unroll
  for (int j = 0; j < 4; ++j) b1[j] = (f16)Wl[l15 * 16 + lhi * 4 + j];
  float cbv = cb[((size_t)((b0 + bz) * 1024 + q)) * 16 + l15];
  __syncthreads();
  // phase 1: logits = S^T x Wl^T, exp, denom; E written in place as rows [g][k]
  float dsum = 0.f;
  for (int i = 0; i < 16; ++i) {
    int kt = w * 16 + i;
    int krow = kt * 16 + l15;
    f16x4 a1;  // A[k][h]: row k=krow, cols h=lhi*4+j
    #pragma unroll
    for (int j = 0; j < 4; ++j) a1[j] = Sl[lhi * 4 + j][krow];
    f32x4 d = __builtin_amdgcn_mfma_f32_16x16x16f16(a1, b1, (f32x4){0.f, 0.f, 0.f, 0.f}, 0, 0, 0);
    int k0 = kt * 16 + lhi * 4;  // D: col g=l15, row k=k0+r
    f16x4 ev;
    #pragma unroll
    for (int r = 0; r < 4; ++r) {
      float e = __expf(d[r] + cbv);
      dsum += e;
      ev[r] = (f16)e;
    }
    *(f16x4*)&Sl[l15][k0] = ev;   // E[g=l15][k0..k0+3], within this wave's k-stripe
  }
  dsum += __shfl_xor(dsum, 16);
  dsum += __shfl_xor(dsum, 32);
  if (lane < 16) red[w][lane] = dsum;
  __syncthreads();
  if (t < 16) rlv16[t] = 1.0f / (red[0][t] + red[1][t] + red[2][t] + red[3][t]);
  __syncthreads();
  // B2[g][h] = Ww[h,g]*rlv[g]; lane: col h=l15, rows g=lhi*4+j
  f16x4 b2;
  #pragma unroll
  for (int j = 0; j < 4; ++j) b2[j] = (f16)(Ww[l15 * 16 + lhi * 4 + j] * rlv16[lhi * 4 + j]);
  float bwh = bwv[l15];
  // phase 2: w = E x (rlv*Ww) + bw, written in place as rows [h][k]
  for (int i = 0; i < 16; ++i) {
    int kt = w * 16 + i;
    int krow = kt * 16 + l15;
    f16x4 a2;  // A[k][g] = E: row k=krow, cols g=lhi*4+j  (stored as Sl[g][k])
    #pragma unroll
    for (int j = 0; j < 4; ++j) a2[j] = Sl[lhi * 4 + j][krow];
    f32x4 d = __builtin_amdgcn_mfma_f32_16x16x16f16(a2, b2, (f32x4){0.f, 0.f, 0.f, 0.f}, 0, 0, 0);
    int k0 = kt * 16 + lhi * 4;  // D: col h=l15, row k=k0+r
    f16x4 wv4;
    #pragma unroll
    for (int r = 0; r < 4; ++r) wv4[r] = (f16)(d[r] + bwh);
    *(f16x4*)&Sl[l15][k0] = wv4;  // w[h=l15][k0..k0+3]
  }
  __syncthreads();
  #pragma unroll
  for (int i = 0; i < 8; ++i) {
    int idx = i * 256 + t, h = idx >> 7, c = (idx & 127) * 8;
    *(f16x8*)(S + Sq + (size_t)h * 1048576 + c) = *(f16x8*)&Sl[h][c];
  }
}

// ---------------- ctx[b*1024+q][h*64+d] = w[h][q][:] @ V[h][:][d]; grid (qt32, h16, bz) ----------------
__global__ __launch_bounds__(256) void pv_gemm(const f16* __restrict__ Sw,
    const f16* __restrict__ Vt, f16* __restrict__ ctx, int b0) {
  alignas(16) __shared__ f16 Aw[32 * 72];
  alignas(16) __shared__ f16 Bv[64 * 72];
  int t = threadIdx.x, lane = t & 63, w = t >> 6;
  int qt = blockIdx.x, h = blockIdx.y, bz = blockIdx.z;
  int wr = w >> 1, wc = w & 1;
  int l15 = lane & 15, lhi = lane >> 4;
  const f16* Sh = Sw + (size_t)(bz * 16 + h) * 1048576 + (size_t)(qt * 32) * 1024;
  const f16* Vh = Vt + (size_t)((b0 + bz) * 16 + h) * 64 * 1024;
  f32x4 acc[2] = {};
  int srow = t >> 3, scol = (t & 7) * 8;
  for (int kk = 0; kk < 1024; kk += 64) {
    __syncthreads();
    *(f16x8*)&Aw[srow * 72 + scol] = *(const f16x8*)(Sh + (size_t)srow * 1024 + kk + scol);
    *(f16x8*)&Bv[srow * 72 + scol] = *(const f16x8*)(Vh + (size_t)srow * 1024 + kk + scol);
    *(f16x8*)&Bv[(srow + 32) * 72 + scol] = *(const f16x8*)(Vh + (size_t)(srow + 32) * 1024 + kk + scol);
    __syncthreads();
    #pragma unroll
    for (int s = 0; s < 2; ++s) {
      f16x8 af = *(const f16x8*)&Aw[(wr * 16 + l15) * 72 + s * 32 + lhi * 8];
      #pragma unroll
      for (int n = 0; n < 2; ++n) {
        f16x8 bf = *(const f16x8*)&Bv[(wc * 32 + n * 16 + l15) * 72 + s * 32 + lhi * 8];
        acc[n] = __builtin_amdgcn_mfma_f32_16x16x32_f16(af, bf, acc[n], 0, 0, 0);
      }
    }
  }
  #pragma unroll
  for (int n = 0; n < 2; ++n) {
    int col = h * 64 + wc * 32 + n * 16 + l15;
    int q0 = (b0 + bz) * 1024 + qt * 32 + wr * 16 + lhi * 4;
    #pragma unroll
    for (int r = 0; r < 4; ++r)
      ctx[(size_t)(q0 + r) * 1024 + col] = (f16)acc[n][r];
  }
}

extern "C" void kernel_launch(void* const* d_in, const int* in_sizes, int n_in,
                              void* d_out, int out_size, void* d_ws, size_t ws_size,
                              hipStream_t stream) {
  const float* queries = (const float*)d_in[0];
  const float* keys    = (const float*)d_in[1];
  const float* values  = (const float*)d_in[2];
  const float* ab  = (const float*)d_in[4];
  const float* Wq  = (const float*)d_in[5];  const float* bq = (const float*)d_in[6];
  const float* Wk  = (const float*)d_in[7];  const float* bk = (const float*)d_in[8];
  const float* Wv  = (const float*)d_in[9];  const float* bv = (const float*)d_in[10];
  const float* Wl  = (const float*)d_in[11]; const float* bl = (const float*)d_in[12];
  const float* Ww  = (const float*)d_in[13]; const float* bwp = (const float*)d_in[14];
  const float* Wo  = (const float*)d_in[15]; const float* bo = (const float*)d_in[16];

  char* ws = (char*)d_ws;
  const size_t MB = 1024 * 1024;
  bool full = ws_size >= 172 * MB;  // deterministic path choice

  // inputs (dead after proj); overlapped by S afterwards
  f16* qin   = (f16*)(ws + 0 * MB);        // 24 MB: q|k|v f16
  f16* wqkv  = (f16*)(ws + 24 * MB);       // 6 MB
  f16* S     = (f16*)(ws + 0 * MB);        // full: 128 MB; chunked: 32 MB per b
  f16* QKVp  = (f16*)(ws + (full ? 128 : 32) * MB);   // 24 MB
  f16* Vt    = (f16*)(ws + (full ? 152 : 56) * MB);   // 8 MB
  float* cbp = (float*)(ws + (full ? 170 : 64) * MB); // 256 KB
  f16* wo16  = (f16*)(ws + (full ? 168 : 65) * MB);   // 2 MB
  f16* ctx   = (f16*)(ws + (full ? 160 : 67) * MB);   // 8 MB
  float* bqkv = (float*)(ws + (full ? 170 * MB + 512 * 1024 : 30 * MB));  // 12 KB

  cvt_all<<<8192, 256, 0, stream>>>(queries, keys, values, Wq, Wk, Wv, Wo, qin, wqkv, wo16);
  biascat<<<12, 256, 0, stream>>>(bq, bk, bv, bqkv);
  proj_gemm<<<dim3(512, 1, 3), 256, 0, stream>>>(qin, wqkv, bqkv, QKVp);
  transpose_v<<<dim3(16, 64), 256, 0, stream>>>(QKVp, Vt);
  cbias_kernel<<<256, 256, 0, stream>>>(ab, Wl, bl, cbp);

  if (full) {
    qk_gemm<<<dim3(8, 8, 64), 256, 0, stream>>>(QKVp, S, 0);
    msm_kernel<<<4096, 256, 0, stream>>>(S, Wl, Ww, bwp, cbp, 0);
    pv_gemm<<<dim3(32, 16, 4), 256, 0, stream>>>(S, Vt, ctx, 0);
  } else {
    for (int b = 0; b < 4; ++b) {
      qk_gemm<<<dim3(8, 8, 16), 256, 0, stream>>>(QKVp, S, b);
      msm_kernel<<<1024, 256, 0, stream>>>(S, Wl, Ww, bwp, cbp, b);
      pv_gemm<<<dim3(32, 16, 1), 256, 0, stream>>>(S, Vt, ctx, b);
    }
  }

  gemm_out<<<dim3(512), 256, 0, stream>>>(ctx, wo16, bo, (float*)d_out);
}